// Round 8
// baseline (389.157 us; speedup 1.0000x reference)
//
#include <hip/hip_runtime.h>
#include <hip/hip_bf16.h>

// GCN on MI355X. Pipeline:
//   k_bhist  - bucket-level histogram (LDS-binned, non-returning global adds)
//   k_bscan  - exclusive scan over <=1024 buckets (single block)
//   k_bucket - bin edges into 128-node dst-buckets; 1 returning atomic per
//              (block,bucket); staging entry packs (src<<7)|dst_local
//   k_sort   - per-bucket LDS counting sort -> exact CSR (sequential writes);
//              also emits rowptr/rowend/dinv
//   k_gemm   - fp32 in, bf16 out; __launch_bounds__(256,4) caps VGPR at 128
//   k_agg    - one wave per node; lane = (edge-slot, feature-group):
//              4 edges in flight, uint2 (4xbf16) gathers, shfl_xor combine
//   k_pool / k_final
// All ws-derived loop bounds are clamped (rocprof counter-replay re-runs
// dispatches against re-poisoned ws; clamps keep those replays sane).

#define BSHIFT 7
#define BNODES (1 << BSHIFT)
#define EPB    8192              // edges per binning block (256 thr x 32)
#define MAXDEG 8192              // clamp for replay-garbage row bounds
#define MAXBUCKET 32768          // clamp for replay-garbage bucket bounds

__device__ __forceinline__ void atomAddF(float* p, float v) {
#if defined(__gfx90a__) || defined(__gfx940__) || defined(__gfx941__) || defined(__gfx942__) || defined(__gfx950__)
    unsafeAtomicAdd(p, v);
#else
    atomicAdd(p, v);
#endif
}

__device__ __forceinline__ unsigned short f2bf(float x) {   // RNE fp32->bf16
    unsigned u = __float_as_uint(x);
    u += 0x7FFFu + ((u >> 16) & 1u);
    return (unsigned short)(u >> 16);
}

// ---------------- bucket histogram ----------------
__global__ __launch_bounds__(256)
void k_bhist(const int* __restrict__ dst, int* __restrict__ bcnt,
             int nE, int nBuckets) {
    __shared__ int cnt[1024];
    const int t = threadIdx.x;
    const int blk = blockIdx.x * EPB;
    for (int b = t; b < nBuckets; b += 256) cnt[b] = 0;
    __syncthreads();
#pragma unroll 4
    for (int i = 0; i < EPB / 256; i++) {
        int e = blk + i * 256 + t;
        if (e < nE) atomicAdd(&cnt[dst[e] >> BSHIFT], 1);
    }
    __syncthreads();
    for (int b = t; b < nBuckets; b += 256) {
        int c = cnt[b];
        if (c > 0) atomicAdd(&bcnt[b], c);   // non-returning: HW-coalesced
    }
}

// ---------------- bucket scan (nb <= 1024), seeds bases + cursors ----------------
__global__ void k_bscan(const int* __restrict__ bcnt, int* __restrict__ bbase,
                        int* __restrict__ bcur, int nb, int nE) {
    __shared__ int s[256];
    const int t = threadIdx.x;
    const int base = t * 4;
    int v0 = (base + 0 < nb) ? bcnt[base + 0] : 0;
    int v1 = (base + 1 < nb) ? bcnt[base + 1] : 0;
    int v2 = (base + 2 < nb) ? bcnt[base + 2] : 0;
    int v3 = (base + 3 < nb) ? bcnt[base + 3] : 0;
    int tsum = v0 + v1 + v2 + v3;
    s[t] = tsum;
    __syncthreads();
    for (int off = 1; off < 256; off <<= 1) {
        int val = 0;
        if (t >= off) val = s[t - off];
        __syncthreads();
        if (t >= off) s[t] += val;
        __syncthreads();
    }
    int excl = s[t] - tsum;
    if (base + 0 < nb) { bbase[base + 0] = excl;               bcur[base + 0] = excl; }
    if (base + 1 < nb) { bbase[base + 1] = excl + v0;          bcur[base + 1] = excl + v0; }
    if (base + 2 < nb) { bbase[base + 2] = excl + v0 + v1;     bcur[base + 2] = excl + v0 + v1; }
    if (base + 3 < nb) { bbase[base + 3] = excl + v0 + v1 + v2; bcur[base + 3] = excl + v0 + v1 + v2; }
    if (t == 0) bbase[nb] = nE;
}

// ---------------- bucket binning: 1 returning atomic per (block,bucket) ----------------
__global__ __launch_bounds__(256)
void k_bucket(const int* __restrict__ src, const int* __restrict__ dst,
              int* __restrict__ bcur, int* __restrict__ staging,
              int nE, int nBuckets) {
    __shared__ int cnt[1024];
    __shared__ int lbase[1024];
    const int t = threadIdx.x;
    const int blk = blockIdx.x * EPB;

    for (int b = t; b < nBuckets; b += 256) cnt[b] = 0;
    __syncthreads();
#pragma unroll 4
    for (int i = 0; i < EPB / 256; i++) {
        int e = blk + i * 256 + t;
        if (e < nE) atomicAdd(&cnt[dst[e] >> BSHIFT], 1);
    }
    __syncthreads();
    for (int b = t; b < nBuckets; b += 256) {
        int c = cnt[b];
        if (c > 0) lbase[b] = atomicAdd(&bcur[b], c);
        cnt[b] = 0;
    }
    __syncthreads();
#pragma unroll 4
    for (int i = 0; i < EPB / 256; i++) {
        int e = blk + i * 256 + t;
        if (e < nE) {
            int s0 = src[e], d0 = dst[e];
            int b = d0 >> BSHIFT;
            int off = atomicAdd(&cnt[b], 1);
            int pos = lbase[b] + off;
            if ((unsigned)pos < (unsigned)nE)
                staging[pos] = (s0 << BSHIFT) | (d0 & (BNODES - 1));
        }
    }
}

// ---------------- per-bucket counting sort -> exact CSR + rowptr/rowend/dinv ----------------
__global__ __launch_bounds__(256)
void k_sort(const int* __restrict__ staging, const int* __restrict__ bbase,
            int* __restrict__ csr_s, int* __restrict__ rowptr,
            int* __restrict__ rowend, float* __restrict__ dinv,
            int n, int nE) {
    __shared__ int c[BNODES];
    __shared__ int sc[BNODES];
    __shared__ int cur[BNODES];
    const int t = threadIdx.x;
    const int b = blockIdx.x;
    const int node0 = b << BSHIFT;

    int seg0 = bbase[b];
    int seg1 = bbase[b + 1];
    seg0 = max(0, min(seg0, nE));
    seg1 = max(seg0, min(seg1, nE));
    seg1 = min(seg1, seg0 + MAXBUCKET);     // replay-garbage guard

    if (t < BNODES) c[t] = 0;
    __syncthreads();
    for (int e = seg0 + t; e < seg1; e += 256)
        atomicAdd(&c[staging[e] & (BNODES - 1)], 1);
    __syncthreads();
    if (t < BNODES) sc[t] = c[t];
    __syncthreads();
    for (int off = 1; off < BNODES; off <<= 1) {
        int v = 0;
        if (t >= off && t < BNODES) v = sc[t - off];
        __syncthreads();
        if (t >= off && t < BNODES) sc[t] += v;
        __syncthreads();
    }
    if (t < BNODES) {
        int excl = sc[t] - c[t];
        cur[t] = excl;
        int node = node0 + t;
        if (node < n) {
            rowptr[node] = seg0 + excl;
            rowend[node] = seg0 + excl + c[t];
            dinv[node]   = rsqrtf((float)c[t] + 1.0f);   // +1 self-loop
        }
    }
    __syncthreads();
    for (int e = seg0 + t; e < seg1; e += 256) {
        int p = staging[e];
        int l = p & (BNODES - 1);
        int pos = seg0 + atomicAdd(&cur[l], 1);
        if ((unsigned)pos < (unsigned)nE)
            csr_s[pos] = ((unsigned)p) >> BSHIFT;
    }
}

// ---------------- GEMM: fp32 in, bf16 out ----------------
// out[n][h] = sum_k act(in[n][k]) * W[k][h]; act = relu(v + bias) when RELU.
template<int LAYER, bool RELU>
__global__ __launch_bounds__(256, 4)
void k_gemm(const float* __restrict__ in, const float* __restrict__ W,
            const float* __restrict__ bias, unsigned short* __restrict__ out, int n) {
    __shared__ float Wl[64 * 64];
    __shared__ float Xl[64 * 68];
    const int t = threadIdx.x;
    const int base = blockIdx.x * 64;

    for (int idx = t; idx < 1024; idx += 256)
        ((float4*)Wl)[idx] = ((const float4*)W)[idx];

    for (int idx = t; idx < 1024; idx += 256) {
        int r = idx >> 4;
        int k4 = (idx & 15) * 4;
        int node = base + r;
        float4 v = make_float4(0.f, 0.f, 0.f, 0.f);
        if (node < n) v = *(const float4*)(in + node * 64 + k4);
        if (RELU) {
            v.x = fmaxf(v.x + bias[k4 + 0], 0.f);
            v.y = fmaxf(v.y + bias[k4 + 1], 0.f);
            v.z = fmaxf(v.z + bias[k4 + 2], 0.f);
            v.w = fmaxf(v.w + bias[k4 + 3], 0.f);
        }
        *(float4*)(Xl + r * 68 + k4) = v;
    }
    __syncthreads();

    const int h4 = (t & 15) * 4;
    const int r4 = (t >> 4) * 4;
    float4 acc[4];
#pragma unroll
    for (int j = 0; j < 4; j++) acc[j] = make_float4(0.f, 0.f, 0.f, 0.f);

#pragma unroll 4
    for (int k4 = 0; k4 < 64; k4 += 4) {
        float4 w0 = *(const float4*)(Wl + (k4 + 0) * 64 + h4);
        float4 w1 = *(const float4*)(Wl + (k4 + 1) * 64 + h4);
        float4 w2 = *(const float4*)(Wl + (k4 + 2) * 64 + h4);
        float4 w3 = *(const float4*)(Wl + (k4 + 3) * 64 + h4);
#pragma unroll
        for (int j = 0; j < 4; j++) {
            float4 x = *(const float4*)(Xl + (r4 + j) * 68 + k4);
            acc[j].x += x.x * w0.x + x.y * w1.x + x.z * w2.x + x.w * w3.x;
            acc[j].y += x.x * w0.y + x.y * w1.y + x.z * w2.y + x.w * w3.y;
            acc[j].z += x.x * w0.z + x.y * w1.z + x.z * w2.z + x.w * w3.z;
            acc[j].w += x.x * w0.w + x.y * w1.w + x.z * w2.w + x.w * w3.w;
        }
    }

#pragma unroll
    for (int j = 0; j < 4; j++) {
        int node = base + r4 + j;
        if (node < n) {
            ushort4 o;
            o.x = f2bf(acc[j].x); o.y = f2bf(acc[j].y);
            o.z = f2bf(acc[j].z); o.w = f2bf(acc[j].w);
            *(ushort4*)(out + node * 64 + h4) = o;
        }
    }
}

// ---------------- aggregation: one wave per node; 4 edges in flight ----------------
// lane = (sub, g): sub = lane>>4 picks edge slot, g = lane&15 covers features
// 4g..4g+3 via one uint2 (4 x bf16). Slot partials combined via shfl_xor.
template<int LAYER>
__global__ __launch_bounds__(256)
void k_agg(const unsigned short* __restrict__ hW, const int* __restrict__ rowptr,
           const int* __restrict__ rowend, const int* __restrict__ csr_s,
           const float* __restrict__ dinv, float* __restrict__ agg, int n, int nE) {
    const int lane = threadIdx.x & 63;
    const int sub  = lane >> 4;        // edge slot 0..3
    const int g    = lane & 15;        // feature group
    const int node = blockIdx.x * 4 + (threadIdx.x >> 6);
    if (node >= n) return;
    int row = rowptr[node];
    int end = rowend[node];
    row = max(0, min(row, nE));
    end = max(row, min(end, nE));
    end = min(end, row + MAXDEG);           // replay-garbage guard
    const float di = dinv[node];

    float a0 = 0.f, a1 = 0.f, a2 = 0.f, a3 = 0.f;

    for (int base = row; base < end; base += 64) {
        const int m = min(64, end - base);
        int   s_l = 0;
        float w_l = 0.f;
        if (base + lane < end) {
            s_l = csr_s[base + lane];
            w_l = dinv[s_l] * di;           // dinv = 400KB, L2-resident
        }
        const int iters = (m + 3) >> 2;
#pragma unroll 4
        for (int j = 0; j < iters; j++) {
            int   idx = 4 * j + sub;        // slots beyond m have w=0
            int   sj = __shfl(s_l, idx);
            float wj = __shfl(w_l, idx);
            uint2 hv = *(const uint2*)(hW + (size_t)sj * 64 + g * 4);
            a0 += wj * __uint_as_float(hv.x << 16);
            a1 += wj * __uint_as_float(hv.x & 0xFFFF0000u);
            a2 += wj * __uint_as_float(hv.y << 16);
            a3 += wj * __uint_as_float(hv.y & 0xFFFF0000u);
        }
    }

    // combine the 4 edge slots (butterfly over lane bits 4,5)
    a0 += __shfl_xor(a0, 16); a0 += __shfl_xor(a0, 32);
    a1 += __shfl_xor(a1, 16); a1 += __shfl_xor(a1, 32);
    a2 += __shfl_xor(a2, 16); a2 += __shfl_xor(a2, 32);
    a3 += __shfl_xor(a3, 16); a3 += __shfl_xor(a3, 32);

    if (sub == 0) {                          // lanes 0..15: self-loop + store
        uint2 hv = *(const uint2*)(hW + (size_t)node * 64 + g * 4);
        float s2 = di * di;
        a0 += s2 * __uint_as_float(hv.x << 16);
        a1 += s2 * __uint_as_float(hv.x & 0xFFFF0000u);
        a2 += s2 * __uint_as_float(hv.y << 16);
        a3 += s2 * __uint_as_float(hv.y & 0xFFFF0000u);
        *(float4*)(agg + (size_t)node * 64 + g * 4) = make_float4(a0, a1, a2, a3);
    }
}

// ---------------- pooling + classifier ----------------

__global__ void k_pool(const float* __restrict__ agg, const int* __restrict__ batch,
                       float* __restrict__ pool, float* __restrict__ cnt, int n) {
    const int lane = threadIdx.x;       // 64 threads
    const int base = blockIdx.x * 64;
    int g_cur = -1, run = 0;
    float acc = 0.f;
    for (int j = 0; j < 64; j++) {
        int node = base + j;
        if (node >= n) break;
        int g = batch[node];
        if (g != g_cur) {
            if (g_cur >= 0) {
                atomAddF(&pool[g_cur * 64 + lane], acc);
                if (lane == 0) atomAddF(&cnt[g_cur], (float)run);
            }
            g_cur = g; acc = 0.f; run = 0;
        }
        acc += agg[node * 64 + lane];
        run++;
    }
    if (g_cur >= 0) {
        atomAddF(&pool[g_cur * 64 + lane], acc);
        if (lane == 0) atomAddF(&cnt[g_cur], (float)run);
    }
}

__global__ void k_final(const float* __restrict__ pool, const float* __restrict__ cnt,
                        const float* __restrict__ b3, const float* __restrict__ Wl,
                        const float* __restrict__ bl, float* __restrict__ out) {
    __shared__ float s[64];
    const int g = blockIdx.x, t = threadIdx.x;
    float c = fmaxf(cnt[g], 1.0f);
    s[t] = pool[g * 64 + t] / c + b3[t];
    __syncthreads();
    if (t < 10) {
        float acc = bl[t];
#pragma unroll
        for (int k = 0; k < 64; k++) acc += s[k] * Wl[k * 10 + t];
        out[g * 10 + t] = acc;
    }
}

extern "C" void kernel_launch(void* const* d_in, const int* in_sizes, int n_in,
                              void* d_out, int out_size, void* d_ws, size_t ws_size,
                              hipStream_t stream) {
    const float* x   = (const float*)d_in[0];
    const int*   ei  = (const int*)d_in[1];
    const int*   bat = (const int*)d_in[2];
    const float* W1  = (const float*)d_in[3];
    const float* b1  = (const float*)d_in[4];
    const float* W2  = (const float*)d_in[5];
    const float* b2  = (const float*)d_in[6];
    const float* W3  = (const float*)d_in[7];
    const float* b3  = (const float*)d_in[8];
    const float* Wl  = (const float*)d_in[9];
    const float* bl  = (const float*)d_in[10];
    float* out = (float*)d_out;

    const int N_ = in_sizes[0] / 64;
    const int E_ = in_sizes[1] / 2;
    const int G_ = out_size / 10;
    const int NB_ = (N_ + BNODES - 1) >> BSHIFT;   // 782 buckets (<=1024)

    // workspace layout (4-byte words; staging/csr first for alignment)
    char* p = (char*)d_ws;
    int*   staging = (int*)p;   p += (size_t)E_ * 4;
    int*   csr_s  = (int*)p;    p += (size_t)E_ * 4;
    float* agg    = (float*)p;  p += (size_t)N_ * 64 * 4;
    unsigned short* hW = (unsigned short*)p; p += (size_t)N_ * 64 * 2;
    float* dinv   = (float*)p;  p += (size_t)N_ * 4;
    int*   rowptr = (int*)p;    p += (size_t)N_ * 4;
    int*   rowend = (int*)p;    p += (size_t)N_ * 4;
    float* pool   = (float*)p;  p += (size_t)G_ * 64 * 4;
    float* cnt    = (float*)p;  p += (size_t)G_ * 4;
    int*   bcnt   = (int*)p;    p += (size_t)(NB_ + 1) * 4;
    int*   bbase  = (int*)p;    p += (size_t)(NB_ + 1) * 4;
    int*   bcur   = (int*)p;    p += (size_t)NB_ * 4;

    const int* srcp = ei;
    const int* dstp = ei + E_;

    hipMemsetAsync(bcnt, 0, (size_t)(NB_ + 1) * 4, stream);
    hipMemsetAsync(pool, 0, (size_t)(G_ * 64 + G_) * 4, stream);

    const int bin_blocks = (E_ + EPB - 1) / EPB;

    k_bhist<<<bin_blocks, 256, 0, stream>>>(dstp, bcnt, E_, NB_);
    k_bscan<<<1, 256, 0, stream>>>(bcnt, bbase, bcur, NB_, E_);
    k_bucket<<<bin_blocks, 256, 0, stream>>>(srcp, dstp, bcur, staging, E_, NB_);
    k_sort<<<NB_, 256, 0, stream>>>(staging, bbase, csr_s, rowptr, rowend,
                                    dinv, N_, E_);

    const int gemm_blocks = (N_ + 63) / 64;
    const int agg_blocks  = (N_ + 3) / 4;

    // Layer 1
    k_gemm<1, false><<<gemm_blocks, 256, 0, stream>>>(x, W1, nullptr, hW, N_);
    k_agg<1><<<agg_blocks, 256, 0, stream>>>(hW, rowptr, rowend, csr_s, dinv,
                                             agg, N_, E_);
    // Layer 2 (relu(prev + b1) on load)
    k_gemm<2, true><<<gemm_blocks, 256, 0, stream>>>(agg, W2, b1, hW, N_);
    k_agg<2><<<agg_blocks, 256, 0, stream>>>(hW, rowptr, rowend, csr_s, dinv,
                                             agg, N_, E_);
    // Layer 3 (relu(prev + b2) on load)
    k_gemm<3, true><<<gemm_blocks, 256, 0, stream>>>(agg, W3, b2, hW, N_);
    k_agg<3><<<agg_blocks, 256, 0, stream>>>(hW, rowptr, rowend, csr_s, dinv,
                                             agg, N_, E_);

    // Pool (b3 folded into final) + classifier
    k_pool<<<(N_ + 63) / 64, 64, 0, stream>>>(agg, bat, pool, cnt, N_);
    k_final<<<G_, 64, 0, stream>>>(pool, cnt, b3, Wl, bl, out);
}

// Round 9
// 352.050 us; speedup vs baseline: 1.1054x; 1.1054x over previous
//
#include <hip/hip_runtime.h>
#include <hip/hip_bf16.h>

// GCN on MI355X. Pipeline:
//   k_bhist/k_bscan/k_bucket/k_sort - bucketed CSR build (as R6/R7)
//   k_wprep - W1..3 fp32 [k][h] -> bf16 Wt [h][k] (B-frag friendly)
//   k_gemm  - MFMA 16x16x32 bf16: A = fp32 input with fused bias+relu+cast,
//             B = Wt bf16, D -> hW bf16. One wave = 16 nodes x 64 h.
//   k_agg   - R7's proven form: one wave per node, lane = feature, bf16 gathers
//   k_pool / k_final
// All ws-derived loop bounds are clamped (rocprof counter-replay re-runs
// dispatches against re-poisoned ws; clamps keep those replays sane).

#define BSHIFT 7
#define BNODES (1 << BSHIFT)
#define EPB    8192
#define MAXDEG 8192
#define MAXBUCKET 32768

typedef __attribute__((ext_vector_type(8))) short bf16x8;
typedef __attribute__((ext_vector_type(4))) float f32x4;

__device__ __forceinline__ void atomAddF(float* p, float v) {
#if defined(__gfx90a__) || defined(__gfx940__) || defined(__gfx941__) || defined(__gfx942__) || defined(__gfx950__)
    unsafeAtomicAdd(p, v);
#else
    atomicAdd(p, v);
#endif
}

__device__ __forceinline__ unsigned short f2bf(float x) {   // RNE fp32->bf16
    unsigned u = __float_as_uint(x);
    u += 0x7FFFu + ((u >> 16) & 1u);
    return (unsigned short)(u >> 16);
}
__device__ __forceinline__ float bf2f(unsigned short b) {
    return __uint_as_float((unsigned)b << 16);
}

// ---------------- bucket histogram ----------------
__global__ __launch_bounds__(256)
void k_bhist(const int* __restrict__ dst, int* __restrict__ bcnt,
             int nE, int nBuckets) {
    __shared__ int cnt[1024];
    const int t = threadIdx.x;
    const int blk = blockIdx.x * EPB;
    for (int b = t; b < nBuckets; b += 256) cnt[b] = 0;
    __syncthreads();
#pragma unroll 4
    for (int i = 0; i < EPB / 256; i++) {
        int e = blk + i * 256 + t;
        if (e < nE) atomicAdd(&cnt[dst[e] >> BSHIFT], 1);
    }
    __syncthreads();
    for (int b = t; b < nBuckets; b += 256) {
        int c = cnt[b];
        if (c > 0) atomicAdd(&bcnt[b], c);
    }
}

// ---------------- bucket scan ----------------
__global__ void k_bscan(const int* __restrict__ bcnt, int* __restrict__ bbase,
                        int* __restrict__ bcur, int nb, int nE) {
    __shared__ int s[256];
    const int t = threadIdx.x;
    const int base = t * 4;
    int v0 = (base + 0 < nb) ? bcnt[base + 0] : 0;
    int v1 = (base + 1 < nb) ? bcnt[base + 1] : 0;
    int v2 = (base + 2 < nb) ? bcnt[base + 2] : 0;
    int v3 = (base + 3 < nb) ? bcnt[base + 3] : 0;
    int tsum = v0 + v1 + v2 + v3;
    s[t] = tsum;
    __syncthreads();
    for (int off = 1; off < 256; off <<= 1) {
        int val = 0;
        if (t >= off) val = s[t - off];
        __syncthreads();
        if (t >= off) s[t] += val;
        __syncthreads();
    }
    int excl = s[t] - tsum;
    if (base + 0 < nb) { bbase[base + 0] = excl;                bcur[base + 0] = excl; }
    if (base + 1 < nb) { bbase[base + 1] = excl + v0;           bcur[base + 1] = excl + v0; }
    if (base + 2 < nb) { bbase[base + 2] = excl + v0 + v1;      bcur[base + 2] = excl + v0 + v1; }
    if (base + 3 < nb) { bbase[base + 3] = excl + v0 + v1 + v2; bcur[base + 3] = excl + v0 + v1 + v2; }
    if (t == 0) bbase[nb] = nE;
}

// ---------------- bucket binning ----------------
__global__ __launch_bounds__(256)
void k_bucket(const int* __restrict__ src, const int* __restrict__ dst,
              int* __restrict__ bcur, int* __restrict__ staging,
              int nE, int nBuckets) {
    __shared__ int cnt[1024];
    __shared__ int lbase[1024];
    const int t = threadIdx.x;
    const int blk = blockIdx.x * EPB;

    for (int b = t; b < nBuckets; b += 256) cnt[b] = 0;
    __syncthreads();
#pragma unroll 4
    for (int i = 0; i < EPB / 256; i++) {
        int e = blk + i * 256 + t;
        if (e < nE) atomicAdd(&cnt[dst[e] >> BSHIFT], 1);
    }
    __syncthreads();
    for (int b = t; b < nBuckets; b += 256) {
        int c = cnt[b];
        if (c > 0) lbase[b] = atomicAdd(&bcur[b], c);
        cnt[b] = 0;
    }
    __syncthreads();
#pragma unroll 4
    for (int i = 0; i < EPB / 256; i++) {
        int e = blk + i * 256 + t;
        if (e < nE) {
            int s0 = src[e], d0 = dst[e];
            int b = d0 >> BSHIFT;
            int off = atomicAdd(&cnt[b], 1);
            int pos = lbase[b] + off;
            if ((unsigned)pos < (unsigned)nE)
                staging[pos] = (s0 << BSHIFT) | (d0 & (BNODES - 1));
        }
    }
}

// ---------------- per-bucket counting sort -> CSR + rowptr/rowend/dinv ----------------
__global__ __launch_bounds__(256)
void k_sort(const int* __restrict__ staging, const int* __restrict__ bbase,
            int* __restrict__ csr_s, int* __restrict__ rowptr,
            int* __restrict__ rowend, float* __restrict__ dinv,
            int n, int nE) {
    __shared__ int c[BNODES];
    __shared__ int sc[BNODES];
    __shared__ int cur[BNODES];
    const int t = threadIdx.x;
    const int b = blockIdx.x;
    const int node0 = b << BSHIFT;

    int seg0 = bbase[b];
    int seg1 = bbase[b + 1];
    seg0 = max(0, min(seg0, nE));
    seg1 = max(seg0, min(seg1, nE));
    seg1 = min(seg1, seg0 + MAXBUCKET);

    if (t < BNODES) c[t] = 0;
    __syncthreads();
    for (int e = seg0 + t; e < seg1; e += 256)
        atomicAdd(&c[staging[e] & (BNODES - 1)], 1);
    __syncthreads();
    if (t < BNODES) sc[t] = c[t];
    __syncthreads();
    for (int off = 1; off < BNODES; off <<= 1) {
        int v = 0;
        if (t >= off && t < BNODES) v = sc[t - off];
        __syncthreads();
        if (t >= off && t < BNODES) sc[t] += v;
        __syncthreads();
    }
    if (t < BNODES) {
        int excl = sc[t] - c[t];
        cur[t] = excl;
        int node = node0 + t;
        if (node < n) {
            rowptr[node] = seg0 + excl;
            rowend[node] = seg0 + excl + c[t];
            dinv[node]   = rsqrtf((float)c[t] + 1.0f);
        }
    }
    __syncthreads();
    for (int e = seg0 + t; e < seg1; e += 256) {
        int p = staging[e];
        int l = p & (BNODES - 1);
        int pos = seg0 + atomicAdd(&cur[l], 1);
        if ((unsigned)pos < (unsigned)nE)
            csr_s[pos] = ((unsigned)p) >> BSHIFT;
    }
}

// ---------------- weight prep: W [k][h] fp32 -> Wt [h][k] bf16 ----------------
__global__ void k_wprep(const float* __restrict__ W1, const float* __restrict__ W2,
                        const float* __restrict__ W3, unsigned short* __restrict__ Wt) {
    const float* W = (blockIdx.x == 0) ? W1 : ((blockIdx.x == 1) ? W2 : W3);
    unsigned short* o = Wt + blockIdx.x * 4096;
    for (int idx = threadIdx.x; idx < 4096; idx += 256) {
        int h = idx >> 6, k = idx & 63;
        o[idx] = f2bf(W[k * 64 + h]);
    }
}

// ---------------- MFMA GEMM: out[n][h] = act(in[n][:]) @ W, bf16 out ----------------
// One wave: 16 nodes x 64 h, K=64 (2 MFMA k-steps x 4 h-tiles = 8 MFMA).
// A[m=lane&15][k=quad*8+j] from fp32 in (bias+relu+bf16 cast fused);
// B[k][n=lane&15] from Wt[h][k] (k-contiguous per lane);
// D col=lane&15 (h), row=quad*4+reg (node).
template<bool RELU>
__global__ __launch_bounds__(256)
void k_gemm(const float* __restrict__ in, const unsigned short* __restrict__ Wt,
            const float* __restrict__ bias, unsigned short* __restrict__ out, int n) {
    const int lane = threadIdx.x & 63;
    const int wid  = threadIdx.x >> 6;
    const int col  = lane & 15;
    const int quad = lane >> 4;
    const int node0w = blockIdx.x * 64 + wid * 16;
    const int nodeA  = node0w + col;          // A-operand row (m)
    const bool validA = nodeA < n;

    f32x4 zero4 = {0.f, 0.f, 0.f, 0.f};
    f32x4 acc0 = zero4, acc1 = zero4, acc2 = zero4, acc3 = zero4;

#pragma unroll
    for (int ks = 0; ks < 64; ks += 32) {
        const int kb = ks + quad * 8;
        float4 a0 = make_float4(0.f, 0.f, 0.f, 0.f);
        float4 a1 = make_float4(0.f, 0.f, 0.f, 0.f);
        if (validA) {
            a0 = *(const float4*)(in + (size_t)nodeA * 64 + kb);
            a1 = *(const float4*)(in + (size_t)nodeA * 64 + kb + 4);
        }
        if (RELU) {
            float4 b0 = *(const float4*)(bias + kb);
            float4 b1 = *(const float4*)(bias + kb + 4);
            a0.x = fmaxf(a0.x + b0.x, 0.f); a0.y = fmaxf(a0.y + b0.y, 0.f);
            a0.z = fmaxf(a0.z + b0.z, 0.f); a0.w = fmaxf(a0.w + b0.w, 0.f);
            a1.x = fmaxf(a1.x + b1.x, 0.f); a1.y = fmaxf(a1.y + b1.y, 0.f);
            a1.z = fmaxf(a1.z + b1.z, 0.f); a1.w = fmaxf(a1.w + b1.w, 0.f);
        }
        bf16x8 af;
        af[0] = (short)f2bf(a0.x); af[1] = (short)f2bf(a0.y);
        af[2] = (short)f2bf(a0.z); af[3] = (short)f2bf(a0.w);
        af[4] = (short)f2bf(a1.x); af[5] = (short)f2bf(a1.y);
        af[6] = (short)f2bf(a1.z); af[7] = (short)f2bf(a1.w);

        const bf16x8 b0f = *(const bf16x8*)(Wt + ((0 * 16 + col) * 64 + kb));
        const bf16x8 b1f = *(const bf16x8*)(Wt + ((1 * 16 + col) * 64 + kb));
        const bf16x8 b2f = *(const bf16x8*)(Wt + ((2 * 16 + col) * 64 + kb));
        const bf16x8 b3f = *(const bf16x8*)(Wt + ((3 * 16 + col) * 64 + kb));
        acc0 = __builtin_amdgcn_mfma_f32_16x16x32_bf16(af, b0f, acc0, 0, 0, 0);
        acc1 = __builtin_amdgcn_mfma_f32_16x16x32_bf16(af, b1f, acc1, 0, 0, 0);
        acc2 = __builtin_amdgcn_mfma_f32_16x16x32_bf16(af, b2f, acc2, 0, 0, 0);
        acc3 = __builtin_amdgcn_mfma_f32_16x16x32_bf16(af, b3f, acc3, 0, 0, 0);
    }

#pragma unroll
    for (int r = 0; r < 4; r++) {
        int nn = node0w + quad * 4 + r;
        if (nn < n) {
            size_t base = (size_t)nn * 64 + col;
            out[base +  0] = f2bf(acc0[r]);
            out[base + 16] = f2bf(acc1[r]);
            out[base + 32] = f2bf(acc2[r]);
            out[base + 48] = f2bf(acc3[r]);
        }
    }
}

// ---------------- aggregation (R7 form): one wave per node, lane = feature ----------------
template<int LAYER>
__global__ __launch_bounds__(256)
void k_agg(const unsigned short* __restrict__ hW, const int* __restrict__ rowptr,
           const int* __restrict__ rowend, const int* __restrict__ csr_s,
           const float* __restrict__ dinv, float* __restrict__ agg, int n, int nE) {
    const int lane = threadIdx.x & 63;
    const int node = blockIdx.x * 4 + (threadIdx.x >> 6);
    if (node >= n) return;
    int row = rowptr[node];
    int end = rowend[node];
    row = max(0, min(row, nE));
    end = max(row, min(end, nE));
    end = min(end, row + MAXDEG);
    const float di = dinv[node];
    float acc0 = di * di * bf2f(hW[(size_t)node * 64 + lane]);   // self-loop
    float acc1 = 0.f, acc2 = 0.f, acc3 = 0.f;

    for (int base = row; base < end; base += 64) {
        const int m = min(64, end - base);
        int   s_l = 0;
        float w_l = 0.f;
        if (base + lane < end) {
            s_l = csr_s[base + lane];
            w_l = dinv[s_l] * di;
        }
        int j = 0;
        for (; j + 8 <= m; j += 8) {
            int   s0 = __shfl(s_l, j),     s1 = __shfl(s_l, j + 1);
            int   s2 = __shfl(s_l, j + 2), s3 = __shfl(s_l, j + 3);
            int   s4 = __shfl(s_l, j + 4), s5 = __shfl(s_l, j + 5);
            int   s6 = __shfl(s_l, j + 6), s7 = __shfl(s_l, j + 7);
            float w0 = __shfl(w_l, j),     w1 = __shfl(w_l, j + 1);
            float w2 = __shfl(w_l, j + 2), w3 = __shfl(w_l, j + 3);
            float w4 = __shfl(w_l, j + 4), w5 = __shfl(w_l, j + 5);
            float w6 = __shfl(w_l, j + 6), w7 = __shfl(w_l, j + 7);
            float h0 = bf2f(hW[(size_t)s0 * 64 + lane]);
            float h1 = bf2f(hW[(size_t)s1 * 64 + lane]);
            float h2 = bf2f(hW[(size_t)s2 * 64 + lane]);
            float h3 = bf2f(hW[(size_t)s3 * 64 + lane]);
            float h4 = bf2f(hW[(size_t)s4 * 64 + lane]);
            float h5 = bf2f(hW[(size_t)s5 * 64 + lane]);
            float h6 = bf2f(hW[(size_t)s6 * 64 + lane]);
            float h7 = bf2f(hW[(size_t)s7 * 64 + lane]);
            acc0 += w0 * h0 + w4 * h4;
            acc1 += w1 * h1 + w5 * h5;
            acc2 += w2 * h2 + w6 * h6;
            acc3 += w3 * h3 + w7 * h7;
        }
        for (; j + 2 <= m; j += 2) {
            int   s0 = __shfl(s_l, j),  s1 = __shfl(s_l, j + 1);
            float w0 = __shfl(w_l, j),  w1 = __shfl(w_l, j + 1);
            acc0 += w0 * bf2f(hW[(size_t)s0 * 64 + lane]);
            acc1 += w1 * bf2f(hW[(size_t)s1 * 64 + lane]);
        }
        for (; j < m; j++) {
            int   sj = __shfl(s_l, j);
            float wj = __shfl(w_l, j);
            acc0 += wj * bf2f(hW[(size_t)sj * 64 + lane]);
        }
    }
    agg[(size_t)node * 64 + lane] = (acc0 + acc1) + (acc2 + acc3);
}

// ---------------- pooling + classifier ----------------

__global__ void k_pool(const float* __restrict__ agg, const int* __restrict__ batch,
                       float* __restrict__ pool, float* __restrict__ cnt, int n) {
    const int lane = threadIdx.x;       // 64 threads
    const int base = blockIdx.x * 64;
    int g_cur = -1, run = 0;
    float acc = 0.f;
    for (int j = 0; j < 64; j++) {
        int node = base + j;
        if (node >= n) break;
        int g = batch[node];
        if (g != g_cur) {
            if (g_cur >= 0) {
                atomAddF(&pool[g_cur * 64 + lane], acc);
                if (lane == 0) atomAddF(&cnt[g_cur], (float)run);
            }
            g_cur = g; acc = 0.f; run = 0;
        }
        acc += agg[node * 64 + lane];
        run++;
    }
    if (g_cur >= 0) {
        atomAddF(&pool[g_cur * 64 + lane], acc);
        if (lane == 0) atomAddF(&cnt[g_cur], (float)run);
    }
}

__global__ void k_final(const float* __restrict__ pool, const float* __restrict__ cnt,
                        const float* __restrict__ b3, const float* __restrict__ Wl,
                        const float* __restrict__ bl, float* __restrict__ out) {
    __shared__ float s[64];
    const int g = blockIdx.x, t = threadIdx.x;
    float c = fmaxf(cnt[g], 1.0f);
    s[t] = pool[g * 64 + t] / c + b3[t];
    __syncthreads();
    if (t < 10) {
        float acc = bl[t];
#pragma unroll
        for (int k = 0; k < 64; k++) acc += s[k] * Wl[k * 10 + t];
        out[g * 10 + t] = acc;
    }
}

extern "C" void kernel_launch(void* const* d_in, const int* in_sizes, int n_in,
                              void* d_out, int out_size, void* d_ws, size_t ws_size,
                              hipStream_t stream) {
    const float* x   = (const float*)d_in[0];
    const int*   ei  = (const int*)d_in[1];
    const int*   bat = (const int*)d_in[2];
    const float* W1  = (const float*)d_in[3];
    const float* b1  = (const float*)d_in[4];
    const float* W2  = (const float*)d_in[5];
    const float* b2  = (const float*)d_in[6];
    const float* W3  = (const float*)d_in[7];
    const float* b3  = (const float*)d_in[8];
    const float* Wl  = (const float*)d_in[9];
    const float* bl  = (const float*)d_in[10];
    float* out = (float*)d_out;

    const int N_ = in_sizes[0] / 64;
    const int E_ = in_sizes[1] / 2;
    const int G_ = out_size / 10;
    const int NB_ = (N_ + BNODES - 1) >> BSHIFT;

    // workspace layout (all blocks 16B-aligned for N,E,G in this problem)
    char* p = (char*)d_ws;
    int*   staging = (int*)p;   p += (size_t)E_ * 4;
    int*   csr_s  = (int*)p;    p += (size_t)E_ * 4;
    float* agg    = (float*)p;  p += (size_t)N_ * 64 * 4;
    unsigned short* hW = (unsigned short*)p; p += (size_t)N_ * 64 * 2;
    float* dinv   = (float*)p;  p += (size_t)N_ * 4;
    int*   rowptr = (int*)p;    p += (size_t)N_ * 4;
    int*   rowend = (int*)p;    p += (size_t)N_ * 4;
    float* pool   = (float*)p;  p += (size_t)G_ * 64 * 4;
    float* cnt    = (float*)p;  p += (size_t)G_ * 4;
    unsigned short* Wt = (unsigned short*)p; p += 3 * 4096 * 2;
    int*   bcnt   = (int*)p;    p += (size_t)(NB_ + 1) * 4;
    int*   bbase  = (int*)p;    p += (size_t)(NB_ + 1) * 4;
    int*   bcur   = (int*)p;    p += (size_t)NB_ * 4;

    const int* srcp = ei;
    const int* dstp = ei + E_;

    hipMemsetAsync(bcnt, 0, (size_t)(NB_ + 1) * 4, stream);
    hipMemsetAsync(pool, 0, (size_t)(G_ * 64 + G_) * 4, stream);

    const int bin_blocks = (E_ + EPB - 1) / EPB;

    k_wprep<<<3, 256, 0, stream>>>(W1, W2, W3, Wt);
    k_bhist<<<bin_blocks, 256, 0, stream>>>(dstp, bcnt, E_, NB_);
    k_bscan<<<1, 256, 0, stream>>>(bcnt, bbase, bcur, NB_, E_);
    k_bucket<<<bin_blocks, 256, 0, stream>>>(srcp, dstp, bcur, staging, E_, NB_);
    k_sort<<<NB_, 256, 0, stream>>>(staging, bbase, csr_s, rowptr, rowend,
                                    dinv, N_, E_);

    const int gemm_blocks = (N_ + 63) / 64;
    const int agg_blocks  = (N_ + 3) / 4;

    // Layer 1
    k_gemm<false><<<gemm_blocks, 256, 0, stream>>>(x, Wt, nullptr, hW, N_);
    k_agg<1><<<agg_blocks, 256, 0, stream>>>(hW, rowptr, rowend, csr_s, dinv,
                                             agg, N_, E_);
    // Layer 2 (relu(prev + b1) fused into A-load)
    k_gemm<true><<<gemm_blocks, 256, 0, stream>>>(agg, Wt + 4096, b1, hW, N_);
    k_agg<2><<<agg_blocks, 256, 0, stream>>>(hW, rowptr, rowend, csr_s, dinv,
                                             agg, N_, E_);
    // Layer 3 (relu(prev + b2) fused into A-load)
    k_gemm<true><<<gemm_blocks, 256, 0, stream>>>(agg, Wt + 8192, b2, hW, N_);
    k_agg<3><<<agg_blocks, 256, 0, stream>>>(hW, rowptr, rowend, csr_s, dinv,
                                             agg, N_, E_);

    // Pool (b3 folded into final) + classifier
    k_pool<<<(N_ + 63) / 64, 64, 0, stream>>>(agg, bat, pool, cnt, N_);
    k_final<<<G_, 64, 0, stream>>>(pool, cnt, b3, Wl, bl, out);
}